// Round 4
// 240.454 us; speedup vs baseline: 1.1107x; 1.1107x over previous
//
#include <hip/hip_runtime.h>
#include <cstdint>
#include <cstddef>

// ---------------------------------------------------------------------------
// Types / helpers
// ---------------------------------------------------------------------------
typedef __attribute__((ext_vector_type(8)))  __bf16 bf16x8;
typedef __attribute__((ext_vector_type(4)))  float  f32x4;
typedef __attribute__((ext_vector_type(16))) float  f32x16;
typedef __attribute__((ext_vector_type(8)))  unsigned short us8;

#define MFMA(a, b, c)   __builtin_amdgcn_mfma_f32_16x16x32_bf16((a), (b), (c), 0, 0, 0)
#define MFMA32(a, b, c) __builtin_amdgcn_mfma_f32_32x32x16_bf16((a), (b), (c), 0, 0, 0)

// 0.125 (=Hd^-0.5) * log2(e): folded into Q so scores come out in log2 domain
#define QSCALE 0.18033688011112042f

__device__ __forceinline__ unsigned short f2bf(float f) {
  unsigned u = __float_as_uint(f);
  u += 0x7fffu + ((u >> 16) & 1u);          // round-to-nearest-even
  return (unsigned short)(u >> 16);
}

// pack two f32 -> one u32 of 2 bf16, low word = first arg.
// Round-half-up via +0x8000 then merge high halves with one v_perm_b32.
// (Proven bit-identical to v_cvt_pk_bf16_f32 in rounds 2/3.)
__device__ __forceinline__ unsigned pk2bf(float lo, float hi) {
  unsigned a = __float_as_uint(lo) + 0x8000u;
  unsigned b = __float_as_uint(hi) + 0x8000u;
  // pool: bytes0-3 = a, bytes4-7 = b; dst = {a.b2,a.b3,b.b2,b.b3}
  return __builtin_amdgcn_perm(b, a, 0x07060302u);
}

// async global -> LDS, 16 B per lane. LDS dest = wave-uniform base + lane*16.
__device__ __forceinline__ void gload16(const void* g, void* l) {
  __builtin_amdgcn_global_load_lds(
      (__attribute__((address_space(1))) unsigned int*)(uintptr_t)g,
      (__attribute__((address_space(3))) unsigned int*)l,
      16, 0, 0);
}

// ---------------------------------------------------------------------------
// fp32 -> bf16 cast, all 7 tensors in one launch (z = tensor index)
// ---------------------------------------------------------------------------
struct CastArgs {
  const float*    src[7];
  unsigned short* dst[7];
  int             n4[7];
};
__global__ __launch_bounds__(256) void cast_kernel(CastArgs a) {
  int z = blockIdx.y;
  const float* __restrict__ in = a.src[z];
  unsigned short* __restrict__ out = a.dst[z];
  int i = blockIdx.x * 256 + threadIdx.x;
  if (i < a.n4[z]) {
    float4 f = ((const float4*)in)[i];
    ushort4 r;
    r.x = f2bf(f.x); r.y = f2bf(f.y); r.z = f2bf(f.z); r.w = f2bf(f.w);
    ((ushort4*)out)[i] = r;
  }
}

// ---------------------------------------------------------------------------
// QKV projection: C[m,n] = (sum_k X[m,k] * W[n,k] + bias[n]) * scl
// z=0 (Q): scl=QSCALE, out [bh][t][hd]
// z=1 (K): scl=1,      out [bh][t][hd]
// z=2 (V): scl=1,      out TRANSPOSED [bh][hd][t] via LDS-transposed epilogue.
// K-loop: double-buffered LDS + counted vmcnt(4) + raw s_barrier so next
// tile's global_load_lds stays in flight across the barrier (T3/T4-lite).
// ---------------------------------------------------------------------------
struct ProjArgs {
  const unsigned short* X[3];
  const unsigned short* W[3];
  const float*          bias[3];
  unsigned short*       out[3];
};

__global__ __launch_bounds__(256) void proj_qkv_kernel(ProjArgs args) {
  // dbuf layout: buf b -> A at smem+b*8192, B at smem+b*8192+4096 (shorts).
  // z=2 epilogue reuses smem[0..8703] as 64 x 136 transpose buffer.
  __shared__ alignas(16) unsigned short smem[16384];

  const int z = blockIdx.z;
  const unsigned short* __restrict__ X   = args.X[z];
  const unsigned short* __restrict__ W   = args.W[z];
  const float* __restrict__ bias         = args.bias[z];
  unsigned short* __restrict__ out       = args.out[z];
  const float scl = (z == 0) ? QSCALE : 1.0f;

  const int t = threadIdx.x;
  const int w = t >> 6, lane = t & 63;
  const int quad = lane >> 4, l15 = lane & 15;
  const int wr = w >> 1, wc = w & 1;
  const int m0 = blockIdx.x * 128, n0 = blockIdx.y * 128;

  const int srow = t >> 2;                              // 0..63
  const int scol = (((t & 3) ^ (srow & 3)) << 3);       // swizzled source chunk

  f32x4 acc[4][4] = {};

  // prologue: stage k0=0 into buf0
  {
    unsigned short* sA = smem;
    unsigned short* sB = smem + 4096;
    gload16(X + (size_t)(m0 + srow) * 512 + scol,      &sA[w * 512]);
    gload16(X + (size_t)(m0 + srow + 64) * 512 + scol, &sA[2048 + w * 512]);
    gload16(W + (size_t)(n0 + srow) * 512 + scol,      &sB[w * 512]);
    gload16(W + (size_t)(n0 + srow + 64) * 512 + scol, &sB[2048 + w * 512]);
  }

  for (int k0 = 0; k0 < 512; k0 += 32) {
    const int buf = (k0 >> 5) & 1;
    unsigned short* sA = smem + buf * 8192;
    unsigned short* sB = sA + 4096;
    if (k0 < 480) {
      unsigned short* nA = smem + (buf ^ 1) * 8192;
      unsigned short* nB = nA + 4096;
      const int kn = k0 + 32;
      gload16(X + (size_t)(m0 + srow) * 512 + kn + scol,      &nA[w * 512]);
      gload16(X + (size_t)(m0 + srow + 64) * 512 + kn + scol, &nA[2048 + w * 512]);
      gload16(W + (size_t)(n0 + srow) * 512 + kn + scol,      &nB[w * 512]);
      gload16(W + (size_t)(n0 + srow + 64) * 512 + kn + scol, &nB[2048 + w * 512]);
      asm volatile("s_waitcnt vmcnt(4)" ::: "memory");   // current tile landed
    } else {
      asm volatile("s_waitcnt vmcnt(0)" ::: "memory");
    }
    __builtin_amdgcn_s_barrier();
    asm volatile("" ::: "memory");

    bf16x8 af[4], bfr[4];
#pragma unroll
    for (int mt = 0; mt < 4; ++mt) {
      int ra = wr * 64 + mt * 16 + l15;
      af[mt] = *(const bf16x8*)&sA[ra * 32 + ((quad ^ (ra & 3)) << 3)];
    }
#pragma unroll
    for (int nt = 0; nt < 4; ++nt) {
      int rb = wc * 64 + nt * 16 + l15;
      bfr[nt] = *(const bf16x8*)&sB[rb * 32 + ((quad ^ (rb & 3)) << 3)];
    }
#pragma unroll
    for (int mt = 0; mt < 4; ++mt)
#pragma unroll
      for (int nt = 0; nt < 4; ++nt)
        acc[mt][nt] = MFMA(af[mt], bfr[nt], acc[mt][nt]);

    asm volatile("" ::: "memory");
    __builtin_amdgcn_s_barrier();     // reads done before buf is overwritten
  }

  if (z != 2) {
    // Q/K epilogue: [bh][t][hd], 32B-contiguous runs per quad (OK)
#pragma unroll
    for (int nt = 0; nt < 4; ++nt) {
      int n = n0 + wc * 64 + nt * 16 + l15;
      float bv = bias[n];
      int h = n >> 6, hd = n & 63;
#pragma unroll
      for (int mt = 0; mt < 4; ++mt) {
#pragma unroll
        for (int r = 0; r < 4; ++r) {
          int m = m0 + wr * 64 + mt * 16 + quad * 4 + r;
          int b = m >> 12, tt = m & 4095;
          out[(((size_t)(b * 8 + h)) * 4096 + tt) * 64 + hd] =
              f2bf((acc[mt][nt][r] + bv) * scl);
        }
      }
    }
  } else {
    // V^T epilogue: stage C^T in LDS (two 64-channel halves), then
    // coalesced 16B/lane stores. V^T flat index: (b*512 + n)*4096 + tt.
    const int b   = m0 >> 12;        // m-range of a block never crosses batch
    const int tt0 = m0 & 4095;
#pragma unroll
    for (int h2 = 0; h2 < 2; ++h2) {
      __syncthreads();               // smem free (loop done / prev half done)
      if (wc == h2) {
#pragma unroll
        for (int nt = 0; nt < 4; ++nt) {
          int nl = nt * 16 + l15;                      // 0..63 within half
          float bv = bias[n0 + h2 * 64 + nl];
#pragma unroll
          for (int mt = 0; mt < 4; ++mt)
#pragma unroll
            for (int r = 0; r < 4; ++r) {
              int ml = wr * 64 + mt * 16 + quad * 4 + r;   // 0..127
              smem[nl * 136 + ml] = f2bf((acc[mt][nt][r] + bv) * scl);
            }
        }
      }
      __syncthreads();
      // 256 threads: 4 lanes/row, each moves 4x us8 (64B) coalesced
      const int row = t >> 2;                  // 0..63 (channel within half)
      const int c4  = (t & 3) * 8;             // 8-short sub-chunk
      const int n   = n0 + h2 * 64 + row;
      unsigned short* dst = out + ((size_t)(b * 512 + n)) * 4096 + tt0;
#pragma unroll
      for (int k = 0; k < 4; ++k)
        *(us8*)(dst + c4 + k * 32) = *(const us8*)&smem[row * 136 + c4 + k * 32];
    }
  }
}

// ---------------------------------------------------------------------------
// Output projection: out[m,n] = sum_k A[m,k] * Wo[n,k] + bo[n]  (fp32 out)
// Same dbuf + counted-vmcnt K-loop as proj_qkv.
// ---------------------------------------------------------------------------
__global__ __launch_bounds__(256) void proj_out_kernel(
    const unsigned short* __restrict__ X, const unsigned short* __restrict__ W,
    const float* __restrict__ bias, float* __restrict__ out) {
  __shared__ alignas(16) unsigned short smem[16384];

  const int t = threadIdx.x;
  const int w = t >> 6, lane = t & 63;
  const int quad = lane >> 4, l15 = lane & 15;
  const int wr = w >> 1, wc = w & 1;
  const int m0 = blockIdx.x * 128, n0 = blockIdx.y * 128;
  const int srow = t >> 2;
  const int scol = (((t & 3) ^ (srow & 3)) << 3);

  f32x4 acc[4][4] = {};

  {
    unsigned short* sA = smem;
    unsigned short* sB = smem + 4096;
    gload16(X + (size_t)(m0 + srow) * 512 + scol,      &sA[w * 512]);
    gload16(X + (size_t)(m0 + srow + 64) * 512 + scol, &sA[2048 + w * 512]);
    gload16(W + (size_t)(n0 + srow) * 512 + scol,      &sB[w * 512]);
    gload16(W + (size_t)(n0 + srow + 64) * 512 + scol, &sB[2048 + w * 512]);
  }

  for (int k0 = 0; k0 < 512; k0 += 32) {
    const int buf = (k0 >> 5) & 1;
    unsigned short* sA = smem + buf * 8192;
    unsigned short* sB = sA + 4096;
    if (k0 < 480) {
      unsigned short* nA = smem + (buf ^ 1) * 8192;
      unsigned short* nB = nA + 4096;
      const int kn = k0 + 32;
      gload16(X + (size_t)(m0 + srow) * 512 + kn + scol,      &nA[w * 512]);
      gload16(X + (size_t)(m0 + srow + 64) * 512 + kn + scol, &nA[2048 + w * 512]);
      gload16(W + (size_t)(n0 + srow) * 512 + kn + scol,      &nB[w * 512]);
      gload16(W + (size_t)(n0 + srow + 64) * 512 + kn + scol, &nB[2048 + w * 512]);
      asm volatile("s_waitcnt vmcnt(4)" ::: "memory");
    } else {
      asm volatile("s_waitcnt vmcnt(0)" ::: "memory");
    }
    __builtin_amdgcn_s_barrier();
    asm volatile("" ::: "memory");

    bf16x8 af[4], bfr[4];
#pragma unroll
    for (int mt = 0; mt < 4; ++mt) {
      int ra = wr * 64 + mt * 16 + l15;
      af[mt] = *(const bf16x8*)&sA[ra * 32 + ((quad ^ (ra & 3)) << 3)];
    }
#pragma unroll
    for (int nt = 0; nt < 4; ++nt) {
      int rb = wc * 64 + nt * 16 + l15;
      bfr[nt] = *(const bf16x8*)&sB[rb * 32 + ((quad ^ (rb & 3)) << 3)];
    }
#pragma unroll
    for (int mt = 0; mt < 4; ++mt)
#pragma unroll
      for (int nt = 0; nt < 4; ++nt)
        acc[mt][nt] = MFMA(af[mt], bfr[nt], acc[mt][nt]);

    asm volatile("" ::: "memory");
    __builtin_amdgcn_s_barrier();
  }

#pragma unroll
  for (int nt = 0; nt < 4; ++nt) {
    int n = n0 + wc * 64 + nt * 16 + l15;
    float bv = bias[n];
#pragma unroll
    for (int mt = 0; mt < 4; ++mt) {
#pragma unroll
      for (int r = 0; r < 4; ++r) {
        int m = m0 + wr * 64 + mt * 16 + quad * 4 + r;
        out[(size_t)m * 512 + n] = acc[mt][nt][r] + bv;
      }
    }
  }
}

// ---------------------------------------------------------------------------
// Flash attention — 32x32 swapped-operand structure.
//   QK^T computed as mfma(K, Q) so C = P^T: lane (q=l31, h=lane>>5) holds
//   P[q][s = 8g + 4h + low2] fully in registers. PV A-frag for k-slice ks
//   needs words: w0/w1 = X/Y[2ks+h] from half h'=0; w2/w3 from half h'=1
//   (X = packed (low2 0,1), Y = (low2 2,3)).
//   Cross-half exchange via __shfl_xor(.,32) + select (KNOWN-correct
//   primitives; the round-1..3 v_permlane32_swap direction was the prime
//   suspect for the deterministic 5e-3 permuted-weights error):
//     L = X[2ks+h] (own), M = X[2ks+1-h] (own), sM = shfl_xor(M,32)
//     w0 = h ? sM : L   (X[2ks+h] from h'=0)
//     w2 = h ? L  : sM  (X[2ks+h] from h'=1)
//   K/V tiles double-buffered, counted s_waitcnt vmcnt(4) + raw s_barrier.
//   Bijective XCD swizzle. Grid (32,16) -> 2 blocks/CU.
// ---------------------------------------------------------------------------
__global__ __launch_bounds__(256, 2) void attn_kernel(
    const unsigned short* __restrict__ Q, const unsigned short* __restrict__ K,
    const unsigned short* __restrict__ VT, unsigned short* __restrict__ Aout) {
  __shared__ alignas(16) unsigned short kt[2][4096];  // [buf][s][d] swizzled
  __shared__ alignas(16) unsigned short vt[2][4096];  // [buf][d][s] swizzled
  __shared__ float lis[128];                          // per-wave row sums

  const int t = threadIdx.x;
  const int w = t >> 6, lane = t & 63;
  const int l31 = lane & 31, h = lane >> 5;

  // bijective XCD swizzle: 512 blocks, 64 per XCD -> 2 bh per XCD L2
  const int wg  = blockIdx.x + gridDim.x * blockIdx.y;     // 0..511
  const int swz = (wg & 7) * 64 + (wg >> 3);
  const int bx = swz & 31, bh = swz >> 5;

  const unsigned short* __restrict__ Qp  = Q  + (size_t)bh * 4096 * 64;
  const unsigned short* __restrict__ Kp  = K  + (size_t)bh * 4096 * 64;
  const unsigned short* __restrict__ VTp = VT + (size_t)bh * 64 * 4096;

  const int q0w = bx * 128 + w * 32;

  const int grow = t >> 3;                              // 0..31 (staging row)
  const int gcol = (((t & 7) ^ (grow & 7)) << 3);       // swizzled source chunk

  // prologue: stage tile 0 into buf 0 (4 DMA ops / wave)
  {
    gload16(Kp + (size_t)grow * 64 + gcol,               &kt[0][w * 512]);
    gload16(Kp + (size_t)(grow + 32) * 64 + gcol,        &kt[0][2048 + w * 512]);
    gload16(VTp + (size_t)grow * 4096 + gcol,            &vt[0][w * 512]);
    gload16(VTp + (size_t)(grow + 32) * 4096 + gcol,     &vt[0][2048 + w * 512]);
  }

  // Q B-frags: lane -> Q[q0w + l31][16*kd + 8*h + j]  (scale pre-folded)
  bf16x8 aq[4];
#pragma unroll
  for (int kd = 0; kd < 4; ++kd)
    aq[kd] = *(const bf16x8*)(Qp + (size_t)(q0w + l31) * 64 + kd * 16 + h * 8);

  f32x16 o0 = {}, o1 = {};
  float li = 0.f;

  const int swzk = (l31 & 7) << 3;        // row-XOR for chunk-swizzled reads
  const int rA0 = l31 * 64, rA1 = (l31 + 32) * 64;

  for (int j = 0; j < 64; ++j) {
    const int cb = j & 1, nb = cb ^ 1;
    if (j < 63) {
      const int s0 = (j + 1) * 64;
      gload16(Kp + (size_t)(s0 + grow) * 64 + gcol,          &kt[nb][w * 512]);
      gload16(Kp + (size_t)(s0 + grow + 32) * 64 + gcol,     &kt[nb][2048 + w * 512]);
      gload16(VTp + (size_t)grow * 4096 + s0 + gcol,         &vt[nb][w * 512]);
      gload16(VTp + (size_t)(grow + 32) * 4096 + s0 + gcol,  &vt[nb][2048 + w * 512]);
      asm volatile("s_waitcnt vmcnt(4)" ::: "memory");  // current tile landed
    } else {
      asm volatile("s_waitcnt vmcnt(0)" ::: "memory");
    }
    __builtin_amdgcn_s_barrier();
    asm volatile("" ::: "memory");

    const unsigned short* ktb = kt[cb];
    const unsigned short* vtb = vt[cb];

    // S^T = K Q^T in log2 domain (2 s-tiles of 32)
    f32x16 scv0 = {}, scv1 = {};
#pragma unroll
    for (int kd = 0; kd < 4; ++kd) {
      bf16x8 k0 = *(const bf16x8*)&ktb[rA0 + ((((2 * kd + h) << 3) ^ swzk))];
      bf16x8 k1 = *(const bf16x8*)&ktb[rA1 + ((((2 * kd + h) << 3) ^ swzk))];
      scv0 = MFMA32(k0, aq[kd], scv0);
      scv1 = MFMA32(k1, aq[kd], scv1);
    }

    // P = exp2(S): fully in-register; accumulate row sum (q = l31 is
    // lane-local, so a plain scalar accumulate is the whole reduction)
    float p0[16], p1[16];
#pragma unroll
    for (int r = 0; r < 16; ++r) {
      p0[r] = __builtin_amdgcn_exp2f(scv0[r]);
      p1[r] = __builtin_amdgcn_exp2f(scv1[r]);
      li += p0[r] + p1[r];
    }

    // pack to bf16 pairs: Xg[g] = (s=8g+4h+0, +1), Yg[g] = (+2, +3)
    unsigned Xg[8], Yg[8];
#pragma unroll
    for (int g = 0; g < 8; ++g) {
      const float* pp = (g < 4) ? p0 : p1;
      const int b4 = (g & 3) * 4;
      Xg[g] = pk2bf(pp[b4 + 0], pp[b4 + 1]);
      Yg[g] = pk2bf(pp[b4 + 2], pp[b4 + 3]);
    }

    // O += P V : A-frag words via shfl_xor(32) + select (known semantics)
#pragma unroll
    for (int ks = 0; ks < 4; ++ks) {
      unsigned Lx = h ? Xg[2 * ks + 1] : Xg[2 * ks];
      unsigned Mx = h ? Xg[2 * ks]     : Xg[2 * ks + 1];
      unsigned Ly = h ? Yg[2 * ks + 1] : Yg[2 * ks];
      unsigned My = h ? Yg[2 * ks]     : Yg[2 * ks + 1];
      unsigned sMx = (unsigned)__shfl_xor((int)Mx, 32, 64);
      unsigned sMy = (unsigned)__shfl_xor((int)My, 32, 64);
      union { unsigned u[4]; bf16x8 v; } pa;
      pa.u[0] = h ? sMx : Lx;     // X[2ks+h] from h'=0  (j=0,1)
      pa.u[1] = h ? sMy : Ly;     // Y[2ks+h] from h'=0  (j=2,3)
      pa.u[2] = h ? Lx  : sMx;    // X[2ks+h] from h'=1  (j=4,5)
      pa.u[3] = h ? Ly  : sMy;    // Y[2ks+h] from h'=1  (j=6,7)
      bf16x8 v0 = *(const bf16x8*)&vtb[rA0 + ((((2 * ks + h) << 3) ^ swzk))];
      bf16x8 v1 = *(const bf16x8*)&vtb[rA1 + ((((2 * ks + h) << 3) ^ swzk))];
      o0 = MFMA32(pa.v, v0, o0);
      o1 = MFMA32(pa.v, v1, o1);
    }

    asm volatile("" ::: "memory");
    __builtin_amdgcn_s_barrier();       // reads done before buf overwrite
  }

  // full row sums: halves of the wave hold complementary s-ranges
  li += __shfl_xor(li, 32);
  if (h == 0) lis[w * 32 + l31] = li;
  __syncthreads();

  // epilogue: normalize, write bf16 to [b][t][h*64+d]
  const int bq = bh >> 3, hh = bh & 7;
#pragma unroll
  for (int r = 0; r < 16; ++r) {
    const int qloc = (r & 3) + 8 * (r >> 2) + 4 * h;
    const float inv = 1.0f / lis[w * 32 + qloc];
    const int trow = q0w + qloc;
    const size_t base = ((size_t)bq * 4096 + trow) * 512 + hh * 64;
    Aout[base + l31]      = f2bf(o0[r] * inv);
    Aout[base + 32 + l31] = f2bf(o1[r] * inv);
  }
}

// ---------------------------------------------------------------------------
// launch
// ---------------------------------------------------------------------------
extern "C" void kernel_launch(void* const* d_in, const int* in_sizes, int n_in,
                              void* d_out, int out_size, void* d_ws, size_t ws_size,
                              hipStream_t stream) {
  (void)in_sizes; (void)n_in; (void)out_size; (void)ws_size;
  const float* query = (const float*)d_in[0];
  const float* key_  = (const float*)d_in[1];
  const float* value = (const float*)d_in[2];
  const float* Wq = (const float*)d_in[3];
  const float* bq = (const float*)d_in[4];
  const float* Wk = (const float*)d_in[5];
  const float* bk = (const float*)d_in[6];
  const float* Wv = (const float*)d_in[7];
  const float* bv = (const float*)d_in[8];
  const float* Wo = (const float*)d_in[9];
  const float* bo = (const float*)d_in[10];
  float* out = (float*)d_out;

  char* ws = (char*)d_ws;
  const size_t MB = 1024 * 1024;
  unsigned short* Xq  = (unsigned short*)(ws + 0 * MB);
  unsigned short* Xk  = (unsigned short*)(ws + 8 * MB);
  unsigned short* Xv  = (unsigned short*)(ws + 16 * MB);
  unsigned short* Wqb = (unsigned short*)(ws + 24 * MB);
  unsigned short* Wkb = (unsigned short*)(ws + 24 * MB + 512 * 1024);
  unsigned short* Wvb = (unsigned short*)(ws + 25 * MB);
  unsigned short* Wob = (unsigned short*)(ws + 25 * MB + 512 * 1024);
  unsigned short* qb  = (unsigned short*)(ws + 26 * MB);
  unsigned short* kb  = (unsigned short*)(ws + 34 * MB);
  unsigned short* vtb = (unsigned short*)(ws + 42 * MB);  // V^T [bh][d][t]
  unsigned short* ao  = Xq;  // alias: Xq dead after qkv projection

  CastArgs ca;
  ca.src[0] = query; ca.src[1] = key_; ca.src[2] = value;
  ca.src[3] = Wq;    ca.src[4] = Wk;   ca.src[5] = Wv;  ca.src[6] = Wo;
  ca.dst[0] = Xq;    ca.dst[1] = Xk;   ca.dst[2] = Xv;
  ca.dst[3] = Wqb;   ca.dst[4] = Wkb;  ca.dst[5] = Wvb; ca.dst[6] = Wob;
  ca.n4[0] = ca.n4[1] = ca.n4[2] = 1048576;
  ca.n4[3] = ca.n4[4] = ca.n4[5] = ca.n4[6] = 65536;
  cast_kernel<<<dim3(4096, 7), 256, 0, stream>>>(ca);

  ProjArgs pa;
  pa.X[0] = Xq;  pa.X[1] = Xk;  pa.X[2] = Xv;
  pa.W[0] = Wqb; pa.W[1] = Wkb; pa.W[2] = Wvb;
  pa.bias[0] = bq; pa.bias[1] = bk; pa.bias[2] = bv;
  pa.out[0] = qb; pa.out[1] = kb; pa.out[2] = vtb;
  proj_qkv_kernel<<<dim3(64, 4, 3), 256, 0, stream>>>(pa);

  attn_kernel<<<dim3(32, 16), 256, 0, stream>>>(qb, kb, vtb, ao);

  proj_out_kernel<<<dim3(64, 4), 256, 0, stream>>>(ao, Wob, bo, out);
}

// Round 5
// 231.087 us; speedup vs baseline: 1.1557x; 1.0405x over previous
//
#include <hip/hip_runtime.h>
#include <cstdint>
#include <cstddef>

// ---------------------------------------------------------------------------
// Types / helpers
// ---------------------------------------------------------------------------
typedef __attribute__((ext_vector_type(8)))  __bf16 bf16x8;
typedef __attribute__((ext_vector_type(4)))  float  f32x4;
typedef __attribute__((ext_vector_type(16))) float  f32x16;
typedef __attribute__((ext_vector_type(8)))  unsigned short us8;

#define MFMA(a, b, c)   __builtin_amdgcn_mfma_f32_16x16x32_bf16((a), (b), (c), 0, 0, 0)
#define MFMA32(a, b, c) __builtin_amdgcn_mfma_f32_32x32x16_bf16((a), (b), (c), 0, 0, 0)

// 0.125 (=Hd^-0.5) * log2(e): folded into Q so scores come out in log2 domain
#define QSCALE 0.18033688011112042f

__device__ __forceinline__ unsigned short f2bf(float f) {
  unsigned u = __float_as_uint(f);
  u += 0x7fffu + ((u >> 16) & 1u);          // round-to-nearest-even
  return (unsigned short)(u >> 16);
}

// pack two f32 -> one u32 of 2 bf16, low word = first arg (round-half-up)
__device__ __forceinline__ unsigned pk2bf(float lo, float hi) {
  unsigned a = __float_as_uint(lo) + 0x8000u;
  unsigned b = __float_as_uint(hi) + 0x8000u;
  return __builtin_amdgcn_perm(b, a, 0x07060302u);
}

// async global -> LDS, 16 B per lane. LDS dest = wave-uniform base + lane*16.
__device__ __forceinline__ void gload16(const void* g, void* l) {
  __builtin_amdgcn_global_load_lds(
      (__attribute__((address_space(1))) unsigned int*)(uintptr_t)g,
      (__attribute__((address_space(3))) unsigned int*)l,
      16, 0, 0);
}

// ---------------------------------------------------------------------------
// fp32 -> bf16 cast, all 7 tensors in one launch (z = tensor index)
// ---------------------------------------------------------------------------
struct CastArgs {
  const float*    src[7];
  unsigned short* dst[7];
  int             n4[7];
};
__global__ __launch_bounds__(256) void cast_kernel(CastArgs a) {
  int z = blockIdx.y;
  const float* __restrict__ in = a.src[z];
  unsigned short* __restrict__ out = a.dst[z];
  int i = blockIdx.x * 256 + threadIdx.x;
  if (i < a.n4[z]) {
    float4 f = ((const float4*)in)[i];
    ushort4 r;
    r.x = f2bf(f.x); r.y = f2bf(f.y); r.z = f2bf(f.z); r.w = f2bf(f.w);
    ((ushort4*)out)[i] = r;
  }
}

// ---------------------------------------------------------------------------
// QKV projection: C[m,n] = (sum_k X[m,k] * W[n,k] + bias[n]) * scl
// z=0 (Q): scl=QSCALE, out [bh][t][hd]
// z=1 (K): scl=1,      out [bh][t][hd]
// z=2 (V): scl=1,      out TRANSPOSED [bh][hd][t] via LDS-transposed epilogue.
// K-loop: double-buffered LDS + counted vmcnt(4) + raw s_barrier.
// ---------------------------------------------------------------------------
struct ProjArgs {
  const unsigned short* X[3];
  const unsigned short* W[3];
  const float*          bias[3];
  unsigned short*       out[3];
};

__global__ __launch_bounds__(256) void proj_qkv_kernel(ProjArgs args) {
  __shared__ alignas(16) unsigned short smem[16384];

  const int z = blockIdx.z;
  const unsigned short* __restrict__ X   = args.X[z];
  const unsigned short* __restrict__ W   = args.W[z];
  const float* __restrict__ bias         = args.bias[z];
  unsigned short* __restrict__ out       = args.out[z];
  const float scl = (z == 0) ? QSCALE : 1.0f;

  const int t = threadIdx.x;
  const int w = t >> 6, lane = t & 63;
  const int quad = lane >> 4, l15 = lane & 15;
  const int wr = w >> 1, wc = w & 1;
  const int m0 = blockIdx.x * 128, n0 = blockIdx.y * 128;

  const int srow = t >> 2;                              // 0..63
  const int scol = (((t & 3) ^ (srow & 3)) << 3);       // swizzled source chunk

  f32x4 acc[4][4] = {};

  {
    unsigned short* sA = smem;
    unsigned short* sB = smem + 4096;
    gload16(X + (size_t)(m0 + srow) * 512 + scol,      &sA[w * 512]);
    gload16(X + (size_t)(m0 + srow + 64) * 512 + scol, &sA[2048 + w * 512]);
    gload16(W + (size_t)(n0 + srow) * 512 + scol,      &sB[w * 512]);
    gload16(W + (size_t)(n0 + srow + 64) * 512 + scol, &sB[2048 + w * 512]);
  }

  for (int k0 = 0; k0 < 512; k0 += 32) {
    const int buf = (k0 >> 5) & 1;
    unsigned short* sA = smem + buf * 8192;
    unsigned short* sB = sA + 4096;
    if (k0 < 480) {
      unsigned short* nA = smem + (buf ^ 1) * 8192;
      unsigned short* nB = nA + 4096;
      const int kn = k0 + 32;
      gload16(X + (size_t)(m0 + srow) * 512 + kn + scol,      &nA[w * 512]);
      gload16(X + (size_t)(m0 + srow + 64) * 512 + kn + scol, &nA[2048 + w * 512]);
      gload16(W + (size_t)(n0 + srow) * 512 + kn + scol,      &nB[w * 512]);
      gload16(W + (size_t)(n0 + srow + 64) * 512 + kn + scol, &nB[2048 + w * 512]);
      asm volatile("s_waitcnt vmcnt(4)" ::: "memory");
    } else {
      asm volatile("s_waitcnt vmcnt(0)" ::: "memory");
    }
    __builtin_amdgcn_s_barrier();
    asm volatile("" ::: "memory");

    bf16x8 af[4], bfr[4];
#pragma unroll
    for (int mt = 0; mt < 4; ++mt) {
      int ra = wr * 64 + mt * 16 + l15;
      af[mt] = *(const bf16x8*)&sA[ra * 32 + ((quad ^ (ra & 3)) << 3)];
    }
#pragma unroll
    for (int nt = 0; nt < 4; ++nt) {
      int rb = wc * 64 + nt * 16 + l15;
      bfr[nt] = *(const bf16x8*)&sB[rb * 32 + ((quad ^ (rb & 3)) << 3)];
    }
#pragma unroll
    for (int mt = 0; mt < 4; ++mt)
#pragma unroll
      for (int nt = 0; nt < 4; ++nt)
        acc[mt][nt] = MFMA(af[mt], bfr[nt], acc[mt][nt]);

    asm volatile("" ::: "memory");
    __builtin_amdgcn_s_barrier();
  }

  if (z != 2) {
#pragma unroll
    for (int nt = 0; nt < 4; ++nt) {
      int n = n0 + wc * 64 + nt * 16 + l15;
      float bv = bias[n];
      int h = n >> 6, hd = n & 63;
#pragma unroll
      for (int mt = 0; mt < 4; ++mt) {
#pragma unroll
        for (int r = 0; r < 4; ++r) {
          int m = m0 + wr * 64 + mt * 16 + quad * 4 + r;
          int b = m >> 12, tt = m & 4095;
          out[(((size_t)(b * 8 + h)) * 4096 + tt) * 64 + hd] =
              f2bf((acc[mt][nt][r] + bv) * scl);
        }
      }
    }
  } else {
    const int b   = m0 >> 12;
    const int tt0 = m0 & 4095;
#pragma unroll
    for (int h2 = 0; h2 < 2; ++h2) {
      __syncthreads();
      if (wc == h2) {
#pragma unroll
        for (int nt = 0; nt < 4; ++nt) {
          int nl = nt * 16 + l15;
          float bv = bias[n0 + h2 * 64 + nl];
#pragma unroll
          for (int mt = 0; mt < 4; ++mt)
#pragma unroll
            for (int r = 0; r < 4; ++r) {
              int ml = wr * 64 + mt * 16 + quad * 4 + r;
              smem[nl * 136 + ml] = f2bf((acc[mt][nt][r] + bv) * scl);
            }
        }
      }
      __syncthreads();
      const int row = t >> 2;
      const int c4  = (t & 3) * 8;
      const int n   = n0 + h2 * 64 + row;
      unsigned short* dst = out + ((size_t)(b * 512 + n)) * 4096 + tt0;
#pragma unroll
      for (int k = 0; k < 4; ++k)
        *(us8*)(dst + c4 + k * 32) = *(const us8*)&smem[row * 136 + c4 + k * 32];
    }
  }
}

// ---------------------------------------------------------------------------
// Output projection: out[m,n] = sum_k A[m,k] * Wo[n,k] + bo[n]  (fp32 out)
// ---------------------------------------------------------------------------
__global__ __launch_bounds__(256) void proj_out_kernel(
    const unsigned short* __restrict__ X, const unsigned short* __restrict__ W,
    const float* __restrict__ bias, float* __restrict__ out) {
  __shared__ alignas(16) unsigned short smem[16384];

  const int t = threadIdx.x;
  const int w = t >> 6, lane = t & 63;
  const int quad = lane >> 4, l15 = lane & 15;
  const int wr = w >> 1, wc = w & 1;
  const int m0 = blockIdx.x * 128, n0 = blockIdx.y * 128;
  const int srow = t >> 2;
  const int scol = (((t & 3) ^ (srow & 3)) << 3);

  f32x4 acc[4][4] = {};

  {
    unsigned short* sA = smem;
    unsigned short* sB = smem + 4096;
    gload16(X + (size_t)(m0 + srow) * 512 + scol,      &sA[w * 512]);
    gload16(X + (size_t)(m0 + srow + 64) * 512 + scol, &sA[2048 + w * 512]);
    gload16(W + (size_t)(n0 + srow) * 512 + scol,      &sB[w * 512]);
    gload16(W + (size_t)(n0 + srow + 64) * 512 + scol, &sB[2048 + w * 512]);
  }

  for (int k0 = 0; k0 < 512; k0 += 32) {
    const int buf = (k0 >> 5) & 1;
    unsigned short* sA = smem + buf * 8192;
    unsigned short* sB = sA + 4096;
    if (k0 < 480) {
      unsigned short* nA = smem + (buf ^ 1) * 8192;
      unsigned short* nB = nA + 4096;
      const int kn = k0 + 32;
      gload16(X + (size_t)(m0 + srow) * 512 + kn + scol,      &nA[w * 512]);
      gload16(X + (size_t)(m0 + srow + 64) * 512 + kn + scol, &nA[2048 + w * 512]);
      gload16(W + (size_t)(n0 + srow) * 512 + kn + scol,      &nB[w * 512]);
      gload16(W + (size_t)(n0 + srow + 64) * 512 + kn + scol, &nB[2048 + w * 512]);
      asm volatile("s_waitcnt vmcnt(4)" ::: "memory");
    } else {
      asm volatile("s_waitcnt vmcnt(0)" ::: "memory");
    }
    __builtin_amdgcn_s_barrier();
    asm volatile("" ::: "memory");

    bf16x8 af[4], bfr[4];
#pragma unroll
    for (int mt = 0; mt < 4; ++mt) {
      int ra = wr * 64 + mt * 16 + l15;
      af[mt] = *(const bf16x8*)&sA[ra * 32 + ((quad ^ (ra & 3)) << 3)];
    }
#pragma unroll
    for (int nt = 0; nt < 4; ++nt) {
      int rb = wc * 64 + nt * 16 + l15;
      bfr[nt] = *(const bf16x8*)&sB[rb * 32 + ((quad ^ (rb & 3)) << 3)];
    }
#pragma unroll
    for (int mt = 0; mt < 4; ++mt)
#pragma unroll
      for (int nt = 0; nt < 4; ++nt)
        acc[mt][nt] = MFMA(af[mt], bfr[nt], acc[mt][nt]);

    asm volatile("" ::: "memory");
    __builtin_amdgcn_s_barrier();
  }

#pragma unroll
  for (int nt = 0; nt < 4; ++nt) {
    int n = n0 + wc * 64 + nt * 16 + l15;
    float bv = bias[n];
#pragma unroll
    for (int mt = 0; mt < 4; ++mt) {
#pragma unroll
      for (int r = 0; r < 4; ++r) {
        int m = m0 + wr * 64 + mt * 16 + quad * 4 + r;
        out[(size_t)m * 512 + n] = acc[mt][nt][r] + bv;
      }
    }
  }
}

// ---------------------------------------------------------------------------
// Flash attention — 32x32 swapped-operand, KVBLK=128, MFMA row-sums.
//   * Each lane (q=l31, h=lane>>5) holds P^T rows in registers; softmax fully
//     in-register; PV A-frags via shfl_xor(32)+select (validated round 4).
//   * KVBLK=128: halves barrier count (32 pairs), K/V double-buffered with
//     counted vmcnt(8) + raw s_barrier (8 DMA ops/wave/tile in flight).
//   * Row-sum li via ones-B MFMA: lsum = mfma32(pa, ones, lsum) reuses the PV
//     A-frag; D[m][n]=Σ_k P = row sum in EXACTLY o0's register layout ->
//     deletes the serial per-tile li add-chain, the lis LDS buffer, the
//     epilogue shfl + __syncthreads.
//   * Bijective XCD swizzle. Grid (32,16) -> 2 blocks/CU.
// ---------------------------------------------------------------------------
__global__ __launch_bounds__(256, 2) void attn_kernel(
    const unsigned short* __restrict__ Q, const unsigned short* __restrict__ K,
    const unsigned short* __restrict__ VT, unsigned short* __restrict__ Aout) {
  __shared__ alignas(16) unsigned short kt[2][8192];  // [buf][s=128][d=64] swz
  __shared__ alignas(16) unsigned short vt[2][8192];  // [buf][d=64][s=128] swz

  const int t = threadIdx.x;
  const int w = t >> 6, lane = t & 63;
  const int l31 = lane & 31, h = lane >> 5;

  // bijective XCD swizzle: 512 blocks, 64 per XCD -> 2 bh per XCD L2
  const int wg  = blockIdx.x + gridDim.x * blockIdx.y;     // 0..511
  const int swz = (wg & 7) * 64 + (wg >> 3);
  const int bx = swz & 31, bh = swz >> 5;

  const unsigned short* __restrict__ Qp  = Q  + (size_t)bh * 4096 * 64;
  const unsigned short* __restrict__ Kp  = K  + (size_t)bh * 4096 * 64;
  const unsigned short* __restrict__ VTp = VT + (size_t)bh * 64 * 4096;

  const int q0w = bx * 128 + w * 32;

  // staging geometry
  const int grow = t >> 3;                               // 0..31 (K row/wave8)
  const int gcol = (((t & 7) ^ (grow & 7)) << 3);        // K source chunk swz
  const int vr4  = w * 4 + ((t & 63) >> 4);              // 0..15 (V row mod16)
  const int vcol = (((t & 15) ^ vr4) << 3);              // V source chunk swz

  // stage tile (s0) into buffer b: K 16KB + V^T 16KB, 8 DMA ops per wave
#define STAGE(bbuf, s0)                                                        \
  {                                                                            \
    _Pragma("unroll")                                                          \
    for (int i = 0; i < 4; ++i)                                                \
      gload16(Kp + (size_t)((s0) + grow + 32 * i) * 64 + gcol,                 \
              &kt[bbuf][i * 2048 + w * 512]);                                  \
    _Pragma("unroll")                                                          \
    for (int i = 0; i < 4; ++i)                                                \
      gload16(VTp + (size_t)(i * 16 + vr4) * 4096 + (s0) + vcol,               \
              &vt[bbuf][(i * 16 + w * 4) * 128]);                              \
  }

  STAGE(0, 0);

  // Q B-frags: lane -> Q[q0w + l31][16*kd + 8*h + j]  (scale pre-folded)
  bf16x8 aq[4];
#pragma unroll
  for (int kd = 0; kd < 4; ++kd)
    aq[kd] = *(const bf16x8*)(Qp + (size_t)(q0w + l31) * 64 + kd * 16 + h * 8);

  // ones B-frag for row-sum MFMA
  union { unsigned short s[8]; bf16x8 v; } one_u;
#pragma unroll
  for (int i = 0; i < 8; ++i) one_u.s[i] = 0x3F80;
  const bf16x8 ones = one_u.v;

  f32x16 o0 = {}, o1 = {}, lsum = {};

  const int swzk = (l31 & 7) << 3;         // K read row-XOR (chunk swizzle)
  const int swzv = (l31 & 15);             // V read row-XOR

  for (int j = 0; j < 32; ++j) {
    const int cb = j & 1, nb = cb ^ 1;
    if (j < 31) {
      STAGE(nb, (j + 1) * 128);
      asm volatile("s_waitcnt vmcnt(8)" ::: "memory");  // current tile landed
    } else {
      asm volatile("s_waitcnt vmcnt(0)" ::: "memory");
    }
    __builtin_amdgcn_s_barrier();
    asm volatile("" ::: "memory");

    const unsigned short* ktb = kt[cb];
    const unsigned short* vtb = vt[cb];

#pragma unroll
    for (int st = 0; st < 4; ++st) {
      // S^T = K Q^T (log2 domain) for s-subtile [st*32, st*32+32)
      f32x16 scv = {};
#pragma unroll
      for (int kd = 0; kd < 4; ++kd) {
        bf16x8 kf = *(const bf16x8*)&ktb[(st * 32 + l31) * 64 +
                                         ((((2 * kd + h) << 3)) ^ swzk)];
        scv = MFMA32(kf, aq[kd], scv);
      }

      // P = exp2(S), pack to bf16 pairs (all in-register)
      float p[16];
#pragma unroll
      for (int r = 0; r < 16; ++r) p[r] = __builtin_amdgcn_exp2f(scv[r]);
      unsigned Xg[4], Yg[4];
#pragma unroll
      for (int g = 0; g < 4; ++g) {
        Xg[g] = pk2bf(p[4 * g + 0], p[4 * g + 1]);
        Yg[g] = pk2bf(p[4 * g + 2], p[4 * g + 3]);
      }

      // O += P V ; lsum += P (ones-B row-sum in o0's layout)
#pragma unroll
      for (int ks = 0; ks < 2; ++ks) {
        unsigned Lx = h ? Xg[2 * ks + 1] : Xg[2 * ks];
        unsigned Mx = h ? Xg[2 * ks]     : Xg[2 * ks + 1];
        unsigned Ly = h ? Yg[2 * ks + 1] : Yg[2 * ks];
        unsigned My = h ? Yg[2 * ks]     : Yg[2 * ks + 1];
        unsigned sMx = (unsigned)__shfl_xor((int)Mx, 32, 64);
        unsigned sMy = (unsigned)__shfl_xor((int)My, 32, 64);
        union { unsigned u[4]; bf16x8 v; } pa;
        pa.u[0] = h ? sMx : Lx;
        pa.u[1] = h ? sMy : Ly;
        pa.u[2] = h ? Lx  : sMx;
        pa.u[3] = h ? Ly  : sMy;
        const int c = st * 4 + 2 * ks + h;             // V^T s-chunk
        bf16x8 v0 = *(const bf16x8*)&vtb[l31 * 128 + ((c ^ swzv) << 3)];
        bf16x8 v1 = *(const bf16x8*)&vtb[(l31 + 32) * 128 + ((c ^ swzv) << 3)];
        o0 = MFMA32(pa.v, v0, o0);
        o1 = MFMA32(pa.v, v1, o1);
        lsum = MFMA32(pa.v, ones, lsum);
      }
    }

    asm volatile("" ::: "memory");
    __builtin_amdgcn_s_barrier();       // reads done before buf overwrite
  }
#undef STAGE

  // epilogue: normalize (lsum[r] = full row sum, same layout as o0[r]),
  // write bf16 to [b][t][h*64+d]
  const int bq = bh >> 3, hh = bh & 7;
#pragma unroll
  for (int r = 0; r < 16; ++r) {
    const int qloc = (r & 3) + 8 * (r >> 2) + 4 * h;
    const float inv = 1.0f / lsum[r];
    const int trow = q0w + qloc;
    const size_t base = ((size_t)bq * 4096 + trow) * 512 + hh * 64;
    Aout[base + l31]      = f2bf(o0[r] * inv);
    Aout[base + 32 + l31] = f2bf(o1[r] * inv);
  }
}

// ---------------------------------------------------------------------------
// launch
// ---------------------------------------------------------------------------
extern "C" void kernel_launch(void* const* d_in, const int* in_sizes, int n_in,
                              void* d_out, int out_size, void* d_ws, size_t ws_size,
                              hipStream_t stream) {
  (void)in_sizes; (void)n_in; (void)out_size; (void)ws_size;
  const float* query = (const float*)d_in[0];
  const float* key_  = (const float*)d_in[1];
  const float* value = (const float*)d_in[2];
  const float* Wq = (const float*)d_in[3];
  const float* bq = (const float*)d_in[4];
  const float* Wk = (const float*)d_in[5];
  const float* bk = (const float*)d_in[6];
  const float* Wv = (const float*)d_in[7];
  const float* bv = (const float*)d_in[8];
  const float* Wo = (const float*)d_in[9];
  const float* bo = (const float*)d_in[10];
  float* out = (float*)d_out;

  char* ws = (char*)d_ws;
  const size_t MB = 1024 * 1024;
  unsigned short* Xq  = (unsigned short*)(ws + 0 * MB);
  unsigned short* Xk  = (unsigned short*)(ws + 8 * MB);
  unsigned short* Xv  = (unsigned short*)(ws + 16 * MB);
  unsigned short* Wqb = (unsigned short*)(ws + 24 * MB);
  unsigned short* Wkb = (unsigned short*)(ws + 24 * MB + 512 * 1024);
  unsigned short* Wvb = (unsigned short*)(ws + 25 * MB);
  unsigned short* Wob = (unsigned short*)(ws + 25 * MB + 512 * 1024);
  unsigned short* qb  = (unsigned short*)(ws + 26 * MB);
  unsigned short* kb  = (unsigned short*)(ws + 34 * MB);
  unsigned short* vtb = (unsigned short*)(ws + 42 * MB);  // V^T [bh][d][t]
  unsigned short* ao  = Xq;  // alias: Xq dead after qkv projection

  CastArgs ca;
  ca.src[0] = query; ca.src[1] = key_; ca.src[2] = value;
  ca.src[3] = Wq;    ca.src[4] = Wk;   ca.src[5] = Wv;  ca.src[6] = Wo;
  ca.dst[0] = Xq;    ca.dst[1] = Xk;   ca.dst[2] = Xv;
  ca.dst[3] = Wqb;   ca.dst[4] = Wkb;  ca.dst[5] = Wvb; ca.dst[6] = Wob;
  ca.n4[0] = ca.n4[1] = ca.n4[2] = 1048576;
  ca.n4[3] = ca.n4[4] = ca.n4[5] = ca.n4[6] = 65536;
  cast_kernel<<<dim3(4096, 7), 256, 0, stream>>>(ca);

  ProjArgs pa;
  pa.X[0] = Xq;  pa.X[1] = Xk;  pa.X[2] = Xv;
  pa.W[0] = Wqb; pa.W[1] = Wkb; pa.W[2] = Wvb;
  pa.bias[0] = bq; pa.bias[1] = bk; pa.bias[2] = bv;
  pa.out[0] = qb; pa.out[1] = kb; pa.out[2] = vtb;
  proj_qkv_kernel<<<dim3(64, 4, 3), 256, 0, stream>>>(pa);

  attn_kernel<<<dim3(32, 16), 256, 0, stream>>>(qb, kb, vtb, ao);

  proj_out_kernel<<<dim3(64, 4), 256, 0, stream>>>(ao, Wob, bo, out);
}